// Round 1
// baseline (416.186 us; speedup 1.0000x reference)
//
#include <hip/hip_runtime.h>

// FilterBank: out[b, band, c, t] = sum_k x[b, c, t + k - 62] * kern[band, k]
// x: (64, 64, 1000) f32, kern: (9, 125) f32, out: (64, 9, 64, 1000) f32.
// lax.conv_general_dilated = cross-correlation (no kernel flip).

#define T_LEN   1000
#define KLEN    125
#define PAD     62
#define NB      9
#define NC      64
#define XS_OFF  64            // x row placed at xs[64] (16B-aligned writes AND reads)
#define XS_LEN  1136          // 64 left halo + 1000 + right halo (max read idx 1131)

__global__ __launch_bounds__(256) void fbank_f32_kernel(
    const float* __restrict__ x,
    const float* __restrict__ kern,
    float* __restrict__ out)
{
    __shared__ float xs[XS_LEN];
    float4* xs4 = reinterpret_cast<float4*>(xs);

    const int tid = threadIdx.x;
    const int bc  = blockIdx.x;            // b*64 + c
    const int b   = bc >> 6;
    const int c   = bc & 63;

    // ---- stage row into LDS ----
    // zero halos: left float4 chunks [0,16), right chunks [266,284)
    const float4 z4 = make_float4(0.f, 0.f, 0.f, 0.f);
    if (tid < 16) xs4[tid] = z4;
    {
        int r = tid - 16;
        if (r >= 0 && r < 18) xs4[266 + r] = z4;
    }
    // x row: 250 float4 chunks -> xs chunks [16, 266)
    {
        const float4* x4 = reinterpret_cast<const float4*>(x + (size_t)bc * T_LEN);
        if (tid < 250) xs4[16 + tid] = x4[tid];
    }
    __syncthreads();

    const int t0 = tid * 4;
    if (t0 < T_LEN) {
        const int cbase = t0 >> 2;                     // chunk idx of float t0
        const size_t out_bc = ((size_t)b * NB) * NC + c; // partial row index (band added in loop)

        for (int band = 0; band < NB; ++band) {
            const float* __restrict__ w = kern + band * KLEN;
            float acc0 = 0.f, acc1 = 0.f, acc2 = 0.f, acc3 = 0.f;

            // register window: xa=[t0+k .. +3], xb=[t0+k+4 ..], xc=[t0+k+8 ..]
            float4 xa = xs4[cbase];
            float4 xb = xs4[cbase + 1];
            float4 xc = xs4[cbase + 2];

            // acc[i] += w[k+u] * xs[t0 + (k+u) + 2 + i]   (e_j = xs[t0+k+j])
            for (int k = 0; k < 124; k += 4) {
                const float w0 = w[k];
                const float w1 = w[k + 1];
                const float w2 = w[k + 2];
                const float w3 = w[k + 3];
                // u=0: e2..e5
                acc0 = fmaf(w0, xa.z, acc0);
                acc1 = fmaf(w0, xa.w, acc1);
                acc2 = fmaf(w0, xb.x, acc2);
                acc3 = fmaf(w0, xb.y, acc3);
                // u=1: e3..e6
                acc0 = fmaf(w1, xa.w, acc0);
                acc1 = fmaf(w1, xb.x, acc1);
                acc2 = fmaf(w1, xb.y, acc2);
                acc3 = fmaf(w1, xb.z, acc3);
                // u=2: e4..e7
                acc0 = fmaf(w2, xb.x, acc0);
                acc1 = fmaf(w2, xb.y, acc1);
                acc2 = fmaf(w2, xb.z, acc2);
                acc3 = fmaf(w2, xb.w, acc3);
                // u=3: e5..e8
                acc0 = fmaf(w3, xb.y, acc0);
                acc1 = fmaf(w3, xb.z, acc1);
                acc2 = fmaf(w3, xb.w, acc2);
                acc3 = fmaf(w3, xc.x, acc3);
                // slide window by one chunk
                xa = xb;
                xb = xc;
                xc = xs4[cbase + (k >> 2) + 3];
            }
            // tail k = 124: acc[i] += w[124] * e_{2+i} (window now at k=124)
            {
                const float w4 = w[124];
                acc0 = fmaf(w4, xa.z, acc0);
                acc1 = fmaf(w4, xa.w, acc1);
                acc2 = fmaf(w4, xb.x, acc2);
                acc3 = fmaf(w4, xb.y, acc3);
            }

            // coalesced float4 store: out[((b*9+band)*64 + c)*1000 + t0 .. +3]
            const size_t row = ((size_t)b * NB + band) * NC + c;
            float4* orow = reinterpret_cast<float4*>(out + row * T_LEN);
            orow[cbase] = make_float4(acc0, acc1, acc2, acc3);
        }
    }
}

extern "C" void kernel_launch(void* const* d_in, const int* in_sizes, int n_in,
                              void* d_out, int out_size, void* d_ws, size_t ws_size,
                              hipStream_t stream) {
    const float* x    = (const float*)d_in[0];
    const float* kern = (const float*)d_in[1];
    float* out = (float*)d_out;

    dim3 grid(64 * 64);   // one block per (b, c) row
    dim3 block(256);
    fbank_f32_kernel<<<grid, block, 0, stream>>>(x, kern, out);
}

// Round 2
// 92.444 us; speedup vs baseline: 4.5020x; 4.5020x over previous
//
#include <hip/hip_runtime.h>

// FilterBank: out[b, band, c, t] = sum_k x[b, c, t + k - 62] * kern[band, k]
// x: (64, 64, 1000) f32, kern: (9, 125) f32, out: (64, 9, 64, 1000) f32.
//
// Round 2: band loop moved INSIDE the k loop — one ds_read_b128 + one window
// slide feeds 9 bands x 16 FMAs = 144 FMAs (was 16). Taps pre-padded to
// (9,128) in d_ws so each 4-tap group is a 16B-aligned wave-uniform
// s_load_dwordx4.

#define T_LEN     1000
#define KLEN      125
#define NB        9
#define NC        64
#define XS_LEN    1136          // 64 left halo + 1000 + right halo (chunks: 284)
#define KW_STRIDE 128

__global__ __launch_bounds__(128) void prep_taps_kernel(
    const float* __restrict__ kern, float* __restrict__ kw)
{
    const int i = threadIdx.x;      // 0..127
    for (int b = 0; b < NB; ++b)
        kw[b * KW_STRIDE + i] = (i < KLEN) ? kern[b * KLEN + i] : 0.f;
}

__global__ __launch_bounds__(256) void fbank_f32_kernel(
    const float* __restrict__ x,
    const float* __restrict__ kw,    // (9,128) zero-padded taps
    float* __restrict__ out)
{
    __shared__ float xs[XS_LEN];
    float4* xs4 = reinterpret_cast<float4*>(xs);

    const int tid = threadIdx.x;
    const int bc  = blockIdx.x;            // b*64 + c
    const int b   = bc >> 6;
    const int c   = bc & 63;

    // ---- stage row into LDS (x[t] lands at xs[64 + t]) ----
    const float4 z4 = make_float4(0.f, 0.f, 0.f, 0.f);
    if (tid < 16) xs4[tid] = z4;                       // left halo chunks [0,16)
    {
        int r = tid - 16;
        if (r >= 0 && r < 18) xs4[266 + r] = z4;       // right halo chunks [266,284)
    }
    {
        const float4* x4 = reinterpret_cast<const float4*>(x + (size_t)bc * T_LEN);
        if (tid < 250) xs4[16 + tid] = x4[tid];        // row chunks [16,266)
    }
    __syncthreads();

    const int t0 = tid * 4;
    if (t0 < T_LEN) {
        const int cbase = t0 >> 2;

        float acc[NB][4];
        #pragma unroll
        for (int band = 0; band < NB; ++band)
            #pragma unroll
            for (int u = 0; u < 4; ++u) acc[band][u] = 0.f;

        // register window: xa=xs[t0+4k .. +3], xb=next chunk, xc=next
        float4 xa = xs4[cbase];
        float4 xb = xs4[cbase + 1];
        float4 xc = xs4[cbase + 2];

        #pragma unroll 1
        for (int k = 0; k < 124; k += 4) {
            #pragma unroll
            for (int band = 0; band < NB; ++band) {
                const float4 w = *reinterpret_cast<const float4*>(kw + band * KW_STRIDE + k);
                // u=0: taps w.x hits xs[t0+k+2+u]
                acc[band][0] = fmaf(w.x, xa.z, acc[band][0]);
                acc[band][1] = fmaf(w.x, xa.w, acc[band][1]);
                acc[band][2] = fmaf(w.x, xb.x, acc[band][2]);
                acc[band][3] = fmaf(w.x, xb.y, acc[band][3]);
                // u=1
                acc[band][0] = fmaf(w.y, xa.w, acc[band][0]);
                acc[band][1] = fmaf(w.y, xb.x, acc[band][1]);
                acc[band][2] = fmaf(w.y, xb.y, acc[band][2]);
                acc[band][3] = fmaf(w.y, xb.z, acc[band][3]);
                // u=2
                acc[band][0] = fmaf(w.z, xb.x, acc[band][0]);
                acc[band][1] = fmaf(w.z, xb.y, acc[band][1]);
                acc[band][2] = fmaf(w.z, xb.z, acc[band][2]);
                acc[band][3] = fmaf(w.z, xb.w, acc[band][3]);
                // u=3
                acc[band][0] = fmaf(w.w, xb.y, acc[band][0]);
                acc[band][1] = fmaf(w.w, xb.z, acc[band][1]);
                acc[band][2] = fmaf(w.w, xb.w, acc[band][2]);
                acc[band][3] = fmaf(w.w, xc.x, acc[band][3]);
            }
            // slide window by one chunk
            xa = xb;
            xb = xc;
            xc = xs4[cbase + (k >> 2) + 3];
        }

        // tail k = 124 (window now at k=124: xa = xs[t0+124 .. +127])
        #pragma unroll
        for (int band = 0; band < NB; ++band) {
            const float w4 = kw[band * KW_STRIDE + 124];
            acc[band][0] = fmaf(w4, xa.z, acc[band][0]);
            acc[band][1] = fmaf(w4, xa.w, acc[band][1]);
            acc[band][2] = fmaf(w4, xb.x, acc[band][2]);
            acc[band][3] = fmaf(w4, xb.y, acc[band][3]);
        }

        // coalesced float4 stores
        #pragma unroll
        for (int band = 0; band < NB; ++band) {
            const size_t row = ((size_t)b * NB + band) * NC + c;
            reinterpret_cast<float4*>(out + row * T_LEN)[cbase] =
                make_float4(acc[band][0], acc[band][1], acc[band][2], acc[band][3]);
        }
    }
}

extern "C" void kernel_launch(void* const* d_in, const int* in_sizes, int n_in,
                              void* d_out, int out_size, void* d_ws, size_t ws_size,
                              hipStream_t stream) {
    const float* x    = (const float*)d_in[0];
    const float* kern = (const float*)d_in[1];
    float* out = (float*)d_out;
    float* kw  = (float*)d_ws;      // (9,128) padded taps

    prep_taps_kernel<<<1, 128, 0, stream>>>(kern, kw);
    fbank_f32_kernel<<<64 * 64, 256, 0, stream>>>(x, kw, out);
}

// Round 3
// 53.501 us; speedup vs baseline: 7.7790x; 1.7279x over previous
//
#include <hip/hip_runtime.h>
#include <hip/hip_bf16.h>

// FilterBank via bf16 MFMA: out[b,band,c,t] = sum_k W[band,k] * x[b,c,t+k-62]
// Per (b,c) row: D[band, t0+j] = sum_k A[band,k] B[k,j],  B[k,j] = xpad[t0+j+k+2]
// (xpad[i] = x[i-64], zero outside [0,1000))
// MFMA 16x16x32 bf16. A = taps (16x128 padded, reg-resident). B = sliding
// window; window(t0+32,kk)==window(t0,kk+1) -> 1 new frag per 16-t tile.
// LDS: 8 shifted bf16 copies (copy r: xpad[i+r]) so every lane's b128 frag
// read is 16B-aligned (lane alignment class r = (j+2)&7 is constant).

#define T_LEN    1000
#define NB       9
#define KP       128
#define S_COPY   1160      // elements per shifted copy (multiple of 8)
#define SLOTS    145       // 16B slots (8 elems) per copy

typedef __attribute__((ext_vector_type(8))) short short8;
typedef __attribute__((ext_vector_type(4))) float f32x4;

__device__ __forceinline__ unsigned int f2bf(float f) {
    union { __hip_bfloat16 h; unsigned short u; } cv;
    cv.h = __float2bfloat16(f);
    return (unsigned int)cv.u;
}

__global__ __launch_bounds__(256) void prep_taps(const float* __restrict__ kern,
                                                 unsigned short* __restrict__ kwb) {
    const int t = threadIdx.x;
    #pragma unroll
    for (int i = 0; i < 8; ++i) {
        int idx = t + 256 * i;            // 0..2047 over [16][128]
        int band = idx >> 7, k = idx & 127;
        float v = (band < NB && k < 125) ? kern[band * 125 + k] : 0.f;
        kwb[idx] = (unsigned short)f2bf(v);
    }
}

__global__ __launch_bounds__(256) void fbank_mfma(
    const float* __restrict__ x,
    const unsigned short* __restrict__ kwb,
    float* __restrict__ out)
{
    __shared__ unsigned short xs[8 * S_COPY];    // 18560 B

    const int tid = threadIdx.x;
    const int bc  = blockIdx.x;                  // b*64 + c
    const int b   = bc >> 6, c = bc & 63;
    const float* xrow = x + (size_t)bc * T_LEN;

    // ---- stage 8 shifted bf16 copies: copy r, slot q = xpad[8q+r .. +7] ----
    {
        const int r = tid >> 5, q0 = tid & 31;
        #pragma unroll
        for (int i = 0; i < 5; ++i) {
            int q = q0 + 32 * i;
            if (q < SLOTS) {
                int idx0 = 8 * q + r - 64;       // x-index of element 0
                unsigned int d[4];
                #pragma unroll
                for (int e2 = 0; e2 < 4; ++e2) {
                    int i0 = idx0 + 2 * e2, i1 = i0 + 1;
                    float v0 = ((unsigned)i0 < T_LEN) ? xrow[i0] : 0.f;
                    float v1 = ((unsigned)i1 < T_LEN) ? xrow[i1] : 0.f;
                    d[e2] = f2bf(v0) | (f2bf(v1) << 16);
                }
                *reinterpret_cast<uint4*>(&xs[r * S_COPY + 8 * q]) =
                    make_uint4(d[0], d[1], d[2], d[3]);
            }
        }
    }

    // ---- A frags (taps), loop-invariant ----
    const int lane = tid & 63;
    const int wid  = tid >> 6;
    const int j = lane & 15, g = lane >> 4;
    short8 a[4];
    #pragma unroll
    for (int kk = 0; kk < 4; ++kk)
        a[kk] = *reinterpret_cast<const short8*>(kwb + j * KP + kk * 32 + g * 8);

    __syncthreads();

    const int t0w = wid << 8;                    // wave owns t in [256w, 256w+256)
    const int rl  = (j + 2) & 7;                 // this lane's alignment class
    const char* xsb = reinterpret_cast<const char*>(xs);
    // window m byte addr = LB + 32*m  (element 1160*rl + (s - rl), s = t0w+2+j+8g+16m)
    const int LB = 2 * (1159 * rl + 2 + j + 8 * g + t0w);

    float* obase = out + ((size_t)b * NB * 64 + c) * T_LEN + t0w + j;
    const int tj = t0w + j;

    short8 w[8];
    #pragma unroll
    for (int m = 0; m < 6; ++m)
        w[m] = *reinterpret_cast<const short8*>(xsb + LB + 32 * m);

    #pragma unroll
    for (int p = 0; p < 8; ++p) {                // tile pair (2p, 2p+1)
        w[(2 * p + 6) & 7] = *reinterpret_cast<const short8*>(xsb + LB + 32 * (2 * p + 6));
        w[(2 * p + 7) & 7] = *reinterpret_cast<const short8*>(xsb + LB + 32 * (2 * p + 7));
        f32x4 ae = {0.f, 0.f, 0.f, 0.f}, ao = {0.f, 0.f, 0.f, 0.f};
        #pragma unroll
        for (int kk = 0; kk < 4; ++kk) {
            ae = __builtin_amdgcn_mfma_f32_16x16x32_bf16(a[kk], w[(2 * p + 2 * kk) & 7], ae, 0, 0, 0);
            ao = __builtin_amdgcn_mfma_f32_16x16x32_bf16(a[kk], w[(2 * p + 1 + 2 * kk) & 7], ao, 0, 0, 0);
        }
        const int te = 32 * p, to = te + 16;
        #pragma unroll
        for (int reg = 0; reg < 4; ++reg) {
            int band = 4 * g + reg;              // D row = 4*(lane>>4) + reg
            if (band < NB) {
                if (tj + te < T_LEN) obase[(size_t)band * 64000 + te] = ae[reg];
                if (tj + to < T_LEN) obase[(size_t)band * 64000 + to] = ao[reg];
            }
        }
    }
}

extern "C" void kernel_launch(void* const* d_in, const int* in_sizes, int n_in,
                              void* d_out, int out_size, void* d_ws, size_t ws_size,
                              hipStream_t stream) {
    const float* x    = (const float*)d_in[0];
    const float* kern = (const float*)d_in[1];
    float* out = (float*)d_out;
    unsigned short* kwb = (unsigned short*)d_ws;   // (16,128) bf16 padded taps

    prep_taps<<<1, 256, 0, stream>>>(kern, kwb);
    fbank_mfma<<<64 * 64, 256, 0, stream>>>(x, kwb, out);
}

// Round 4
// 51.706 us; speedup vs baseline: 8.0491x; 1.0347x over previous
//
#include <hip/hip_runtime.h>
#include <hip/hip_bf16.h>

// FilterBank via bf16 MFMA: out[b,band,c,t] = sum_k W[band,k] * x[b,c,t+k-62]
// Per (b,c) row: D[band, t0+j] = sum_k A[band,k] B[k,j],  B[k,j] = xpad[t0+j+k+2]
// MFMA 16x16x32 bf16, A = taps (reg-resident), B = sliding window ring (1 new
// frag per 16-t tile). 8 shifted bf16 LDS copies make every window read a
// 16B-aligned ds_read_b128.
// Round 4: LDS-transpose epilogue — tiles staged to per-wave [9][132] f32
// buffer, flushed as 1KB-contiguous float4 stores per band (was 128 scalar
// stores/wave with masked lanes).

#define T_LEN    1000
#define NB       9
#define KP       128
#define S_COPY   1160      // elements per shifted copy (multiple of 8)
#define SLOTS    145       // 16B slots (8 elems) per copy
#define STG_W    132       // staging floats per band row (128 + 4 pad)

typedef __attribute__((ext_vector_type(8))) short short8;
typedef __attribute__((ext_vector_type(4))) float f32x4;

__device__ __forceinline__ unsigned int f2bf(float f) {
    union { __hip_bfloat16 h; unsigned short u; } cv;
    cv.h = __float2bfloat16(f);
    return (unsigned int)cv.u;
}

__global__ __launch_bounds__(256) void prep_taps(const float* __restrict__ kern,
                                                 unsigned short* __restrict__ kwb) {
    const int t = threadIdx.x;
    #pragma unroll
    for (int i = 0; i < 8; ++i) {
        int idx = t + 256 * i;            // 0..2047 over [16][128]
        int band = idx >> 7, k = idx & 127;
        float v = (band < NB && k < 125) ? kern[band * 125 + k] : 0.f;
        kwb[idx] = (unsigned short)f2bf(v);
    }
}

__global__ __launch_bounds__(256) void fbank_mfma(
    const float* __restrict__ x,
    const unsigned short* __restrict__ kwb,
    float* __restrict__ out)
{
    __shared__ unsigned short xs[8 * S_COPY];          // 18560 B
    __shared__ float stg[4 * NB * STG_W];              // 19008 B, per-wave [9][132]

    const int tid = threadIdx.x;
    const int bc  = blockIdx.x;                  // b*64 + c
    const int b   = bc >> 6, c = bc & 63;
    const float* xrow = x + (size_t)bc * T_LEN;

    // ---- stage 8 shifted bf16 copies: copy r, slot q = xpad[8q+r .. +7] ----
    {
        const int r = tid >> 5, q0 = tid & 31;
        #pragma unroll
        for (int i = 0; i < 5; ++i) {
            int q = q0 + 32 * i;
            if (q < SLOTS) {
                int idx0 = 8 * q + r - 64;       // x-index of element 0
                unsigned int d[4];
                #pragma unroll
                for (int e2 = 0; e2 < 4; ++e2) {
                    int i0 = idx0 + 2 * e2, i1 = i0 + 1;
                    float v0 = ((unsigned)i0 < T_LEN) ? xrow[i0] : 0.f;
                    float v1 = ((unsigned)i1 < T_LEN) ? xrow[i1] : 0.f;
                    d[e2] = f2bf(v0) | (f2bf(v1) << 16);
                }
                *reinterpret_cast<uint4*>(&xs[r * S_COPY + 8 * q]) =
                    make_uint4(d[0], d[1], d[2], d[3]);
            }
        }
    }

    // ---- A frags (taps), loop-invariant ----
    const int lane = tid & 63;
    const int wid  = tid >> 6;
    const int j = lane & 15, g = lane >> 4;
    short8 a[4];
    #pragma unroll
    for (int kk = 0; kk < 4; ++kk)
        a[kk] = *reinterpret_cast<const short8*>(kwb + j * KP + kk * 32 + g * 8);

    __syncthreads();

    const int t0w = wid << 8;                    // wave owns t in [256w, 256w+256)
    const int rl  = (j + 2) & 7;                 // this lane's alignment class
    const char* xsb = reinterpret_cast<const char*>(xs);
    // window m byte addr = LB + 32*m  (element 1160*rl + (s - rl), s = t0w+2+j+8g+16m)
    const int LB = 2 * (1159 * rl + 2 + j + 8 * g + t0w);

    float* sw = stg + wid * (NB * STG_W);        // this wave's staging buffer

    short8 w[8];
    #pragma unroll
    for (int m = 0; m < 6; ++m)
        w[m] = *reinterpret_cast<const short8*>(xsb + LB + 32 * m);

    for (int ch = 0; ch < 2; ++ch) {             // two 128-t chunks
        #pragma unroll
        for (int pp = 0; pp < 4; ++pp) {         // tile pairs within chunk
            const int p = ch * 4 + pp;
            w[(2 * p + 6) & 7] = *reinterpret_cast<const short8*>(xsb + LB + 32 * (2 * p + 6));
            w[(2 * p + 7) & 7] = *reinterpret_cast<const short8*>(xsb + LB + 32 * (2 * p + 7));
            f32x4 ae = {0.f, 0.f, 0.f, 0.f}, ao = {0.f, 0.f, 0.f, 0.f};
            #pragma unroll
            for (int kk = 0; kk < 4; ++kk) {
                ae = __builtin_amdgcn_mfma_f32_16x16x32_bf16(a[kk], w[(2 * p + 2 * kk) & 7], ae, 0, 0, 0);
                ao = __builtin_amdgcn_mfma_f32_16x16x32_bf16(a[kk], w[(2 * p + 1 + 2 * kk) & 7], ao, 0, 0, 0);
            }
            // stage tiles: D row = band = 4g + reg, col = t offset j
            const int tloc = 32 * pp + j;
            #pragma unroll
            for (int reg = 0; reg < 4; ++reg) {
                int band = 4 * g + reg;
                if (band < NB) {
                    sw[band * STG_W + tloc]      = ae[reg];
                    sw[band * STG_W + tloc + 16] = ao[reg];
                }
            }
        }
        // flush chunk: per band, 128 contiguous floats -> 32 float4 chunks
        const int tcb = t0w + 128 * ch;
        #pragma unroll
        for (int it = 0; it < 5; ++it) {
            int flat = it * 64 + lane;           // 0..319 (need < 288)
            int bb = flat >> 5, cc = flat & 31;
            if (bb < NB) {
                int t = tcb + 4 * cc;
                if (t + 4 <= T_LEN) {
                    f32x4 v = *reinterpret_cast<const f32x4*>(sw + bb * STG_W + 4 * cc);
                    *reinterpret_cast<f32x4*>(
                        out + (((size_t)b * NB + bb) * 64 + c) * T_LEN + t) = v;
                }
            }
        }
    }
}

extern "C" void kernel_launch(void* const* d_in, const int* in_sizes, int n_in,
                              void* d_out, int out_size, void* d_ws, size_t ws_size,
                              hipStream_t stream) {
    const float* x    = (const float*)d_in[0];
    const float* kern = (const float*)d_in[1];
    float* out = (float*)d_out;
    unsigned short* kwb = (unsigned short*)d_ws;   // (16,128) bf16 padded taps

    prep_taps<<<1, 256, 0, stream>>>(kern, kwb);
    fbank_mfma<<<64 * 64, 256, 0, stream>>>(x, kwb, out);
}